// Round 6
// baseline (574.724 us; speedup 1.0000x reference)
//
#include <hip/hip_runtime.h>
#include <hip/hip_cooperative_groups.h>
#include <stdint.h>

namespace cg = cooperative_groups;

typedef __attribute__((ext_vector_type(8))) short short8;
typedef __attribute__((ext_vector_type(4))) short short4_t;
typedef __attribute__((ext_vector_type(4))) float f32x4;
typedef __attribute__((ext_vector_type(2))) unsigned int u32x2;
typedef unsigned short u16;
typedef unsigned int u32;

#define C_ 512

__device__ __forceinline__ u16 f2b(float f){
  u32 u = __float_as_uint(f);
  u += 0x7FFFu + ((u >> 16) & 1u);
  return (u16)(u >> 16);
}
__device__ __forceinline__ float b2f(u16 h){ return __uint_as_float(((u32)h) << 16); }

__device__ __forceinline__ short8 cvt8(float4 lo, float4 hi){
  short8 r;
  r[0]=(short)f2b(lo.x); r[1]=(short)f2b(lo.y); r[2]=(short)f2b(lo.z); r[3]=(short)f2b(lo.w);
  r[4]=(short)f2b(hi.x); r[5]=(short)f2b(hi.y); r[6]=(short)f2b(hi.z); r[7]=(short)f2b(hi.w);
  return r;
}

// =================== fused cooperative kernel ===================
// grid 1024 x 256 (4 blocks/CU co-resident). Block bx owns rows [bx*128, bx*128+128).
__global__ __launch_bounds__(256, 4) void fused(
    const float* __restrict__ x,
    const float* __restrict__ Wq, const float* __restrict__ bq,
    const float* __restrict__ Wk, const float* __restrict__ bk,
    const float* __restrict__ Wv, const float* __restrict__ bv,
    const float* __restrict__ Wp, const float* __restrict__ bp,
    const float* __restrict__ agent_k, const float* __restrict__ agent_v,
    const float* __restrict__ ca_w1, const float* __restrict__ ca_w2,
    float* __restrict__ out,
    float* __restrict__ k2, float* __restrict__ v2,
    u16* __restrict__ WqkT, float* __restrict__ bqk,
    u16* __restrict__ WvpT, float* __restrict__ gpart)
{
  cg::grid_group gg = cg::this_grid();
  __shared__ __align__(16) char raw[32768];       // WqkT-stage | P | W-stage (time-shared)
  __shared__ float ps[4][16], pm[4][16], gsh[16], vsh[64];

  const int bx = blockIdx.x, t = threadIdx.x;
  const int w = t >> 6, lane = t & 63;
  const int la = lane & 15, rg = lane >> 4;

  // ---------- pre-1: k2/v2 = agent @ W + b (blocks 0..63) ----------
  if (bx < 64) {
    const int kv = bx >> 5, c0 = (bx & 31) * 16;
    const float* ag = kv ? agent_v : agent_k;
    const float* W  = kv ? Wv : Wk;
    const float* bb = kv ? bv : bk;
    float* dst = kv ? v2 : k2;
    float* part = (float*)raw;                    // 16 KB
    const int cl = t & 15, ks = t >> 4;
    float s[16];
    #pragma unroll
    for (int a = 0; a < 16; ++a) s[a] = 0.f;
    for (int i = 0; i < 32; ++i) {
      const int cc = ks*32 + i;
      const float wv = W[(size_t)cc*C_ + c0 + cl];
      #pragma unroll
      for (int a = 0; a < 16; ++a) s[a] += ag[a*C_ + cc] * wv;
    }
    #pragma unroll
    for (int a = 0; a < 16; ++a) part[ks*256 + a*16 + cl] = s[a];
    __syncthreads();
    {
      const int a = t >> 4, c = t & 15;
      float v = bb[c0 + c];
      #pragma unroll
      for (int k = 0; k < 16; ++k) v += part[k*256 + a*16 + c];
      dst[a*C_ + c0 + c] = v;
    }
  }
  gg.sync();

  // ---------- pre-2: WqkT (blocks 0..511), WvpT (blocks 512..639) ----------
  if (bx < 512) {
    if (t < 128) {
      const int c = bx, h = t >> 4, a = t & 15;
      float s = 0.f;
      #pragma unroll
      for (int d = 0; d < 64; ++d) s += Wq[c*C_ + h*64 + d] * k2[a*C_ + h*64 + d];
      WqkT[t*C_ + c] = f2b(s * 0.125f);
      if (c == 0) {
        float sb = 0.f;
        #pragma unroll
        for (int d = 0; d < 64; ++d) sb += bq[h*64 + d] * k2[a*C_ + h*64 + d];
        bqk[t] = sb * 0.125f;
      }
    }
  } else if (bx < 640) {
    const int ha = bx - 512, h = ha >> 4, a = ha & 15;
    if (t < 64) vsh[t] = v2[a*C_ + h*64 + t];
    __syncthreads();
    for (int co = t; co < C_; co += 256) {
      float s = 0.f;
      #pragma unroll
      for (int d = 0; d < 64; ++d) s += vsh[d] * Wp[(h*64 + d)*C_ + co];
      WvpT[co*128 + ha] = f2b(s);
    }
  }
  gg.sync();

  // ---------- phase A: scores GEMM + softmax (rows bx*128..+128) ----------
  const int m0 = bx * 128;
  const float* xr0 = x + (size_t)(m0 + w*32 + la)*C_ + rg*8;
  const float* xr1 = xr0 + 16*C_;

  const int srow = t >> 1, shalf = t & 1;
  const u16* ssrc = WqkT + (size_t)srow*C_ + shalf*64;
  char* sdst = (char*)raw + srow*256;
  const int sxor = (srow & 7) << 4;

  f32x4 acc[2][8];
  #pragma unroll
  for (int i = 0; i < 2; ++i)
    #pragma unroll
    for (int j = 0; j < 8; ++j) acc[i][j] = (f32x4){0.f,0.f,0.f,0.f};

  float4 pr0[2][2], pr1[2][2];                     // depth-2 kt ring
#define LOADKT(slot, kt) \
  pr0[slot][0] = *(const float4*)(xr0 + (kt)*32);     \
  pr0[slot][1] = *(const float4*)(xr0 + (kt)*32 + 4); \
  pr1[slot][0] = *(const float4*)(xr1 + (kt)*32);     \
  pr1[slot][1] = *(const float4*)(xr1 + (kt)*32 + 4);

  LOADKT(0, 0); LOADKT(1, 1);

  #pragma unroll
  for (int ph = 0; ph < 4; ++ph) {
    __syncthreads();
    #pragma unroll
    for (int i = 0; i < 8; ++i) {
      short8 v = *(const short8*)(ssrc + ph*128 + i*8);
      *(short8*)(sdst + ((shalf*128 + i*16) ^ sxor)) = v;
    }
    __syncthreads();
    #pragma unroll
    for (int k4 = 0; k4 < 4; ++k4) {
      const int kt = ph*4 + k4;
      const int sl = kt & 1;
      short8 b0 = cvt8(pr0[sl][0], pr0[sl][1]);
      short8 b1 = cvt8(pr1[sl][0], pr1[sl][1]);
      if (kt < 14) { LOADKT(sl, kt + 2); }
      #pragma unroll
      for (int ct = 0; ct < 8; ++ct) {
        const int row = ct*16 + la;
        short8 af = *(const short8*)((const char*)raw + row*256 + ((k4*64 + rg*16) ^ ((row & 7) << 4)));
        acc[0][ct] = __builtin_amdgcn_mfma_f32_16x16x32_bf16(af, b0, acc[0][ct], 0, 0, 0);
        acc[1][ct] = __builtin_amdgcn_mfma_f32_16x16x32_bf16(af, b1, acc[1][ct], 0, 0, 0);
      }
    }
  }
#undef LOADKT

  // softmax over a (in-register) -> pk (bf16 pairs), gating partials
  float psj[4] = {0.f,0.f,0.f,0.f};
  float pmj[4] = {0.f,0.f,0.f,0.f};
  u32 pk[2][8][2];

  #pragma unroll
  for (int nt = 0; nt < 2; ++nt) {
    #pragma unroll
    for (int ct = 0; ct < 8; ++ct) {
      float4 bb = *(const float4*)(bqk + ct*16 + rg*4);
      float e0 = __expf(acc[nt][ct][0] + bb.x);
      float e1 = __expf(acc[nt][ct][1] + bb.y);
      float e2 = __expf(acc[nt][ct][2] + bb.z);
      float e3 = __expf(acc[nt][ct][3] + bb.w);
      float s = e0 + e1 + e2 + e3;
      s += __shfl_xor(s, 16); s += __shfl_xor(s, 32);
      float r = __builtin_amdgcn_rcpf(s);
      float p0 = e0*r, p1 = e1*r, p2 = e2*r, p3 = e3*r;
      psj[0] += p0; psj[1] += p1; psj[2] += p2; psj[3] += p3;
      pmj[0] = fmaxf(pmj[0], p0); pmj[1] = fmaxf(pmj[1], p1);
      pmj[2] = fmaxf(pmj[2], p2); pmj[3] = fmaxf(pmj[3], p3);
      pk[nt][ct][0] = (u32)f2b(p0) | ((u32)f2b(p1) << 16);
      pk[nt][ct][1] = (u32)f2b(p2) | ((u32)f2b(p3) << 16);
    }
  }

  #pragma unroll
  for (int j = 0; j < 4; ++j) {
    float s = psj[j], m = pmj[j];
    s += __shfl_xor(s, 1); s += __shfl_xor(s, 2); s += __shfl_xor(s, 4); s += __shfl_xor(s, 8);
    m = fmaxf(m, __shfl_xor(m, 1)); m = fmaxf(m, __shfl_xor(m, 2));
    m = fmaxf(m, __shfl_xor(m, 4)); m = fmaxf(m, __shfl_xor(m, 8));
    if (la == 0) { ps[w][rg*4+j] = s; pm[w][rg*4+j] = m; }
  }
  __syncthreads();                                 // Bs reads done; ps/pm visible

  // P -> LDS (swizzled), gpart write
  #pragma unroll
  for (int nt = 0; nt < 2; ++nt) {
    const int row = w*32 + nt*16 + la;
    const int rx = (row & 7) << 4;
    #pragma unroll
    for (int ct = 0; ct < 8; ++ct) {
      u32x2 v; v.x = pk[nt][ct][0]; v.y = pk[nt][ct][1];
      *(u32x2*)((char*)raw + row*256 + ((ct*32 + rg*8) ^ rx)) = v;
    }
  }
  if (t < 16) {
    float s = ps[0][t] + ps[1][t] + ps[2][t] + ps[3][t];
    float m = fmaxf(fmaxf(pm[0][t], pm[1][t]), fmaxf(pm[2][t], pm[3][t]));
    gpart[(size_t)bx*32 + t]      = s;
    gpart[(size_t)bx*32 + 16 + t] = m;
  }
  gg.sync();

  // ---------- gate MLP + read P back as B-fragments ----------
  if (t < 16) {
    const int b = bx >> 5;
    float s = 0.f, m = 0.f;
    #pragma unroll 4
    for (int blk = 0; blk < 32; ++blk) {
      const float* gp = gpart + (size_t)(b*32 + blk)*32;
      s += gp[t]; m = fmaxf(m, gp[16 + t]);
    }
    float c1 = s * (1.0f/32768.0f) * ca_w1[t];
    float c2 = m * ca_w1[t];
    c1 += __shfl_xor(c1, 1); c1 += __shfl_xor(c1, 2); c1 += __shfl_xor(c1, 4); c1 += __shfl_xor(c1, 8);
    c2 += __shfl_xor(c2, 1); c2 += __shfl_xor(c2, 2); c2 += __shfl_xor(c2, 4); c2 += __shfl_xor(c2, 8);
    float g1 = fmaxf(c1, 0.f) + fmaxf(c2, 0.f);
    gsh[t] = 1.f / (1.f + __expf(-g1 * ca_w2[t]));
  }
  short8 bfr[2][4];
  #pragma unroll
  for (int nt = 0; nt < 2; ++nt) {
    const int row = w*32 + nt*16 + la;
    const int rx = (row & 7) << 4;
    #pragma unroll
    for (int kt = 0; kt < 4; ++kt)
      bfr[nt][kt] = *(const short8*)((const char*)raw + row*256 + ((kt*64 + rg*16) ^ rx));
  }
  __syncthreads();                                 // gsh ready, P reads retired

  // gate folded into P-fragments: a = (rg&1)*8 + e
  float ge[8];
  #pragma unroll
  for (int e = 0; e < 8; ++e) ge[e] = gsh[(rg & 1)*8 + e];
  #pragma unroll
  for (int nt = 0; nt < 2; ++nt)
    #pragma unroll
    for (int kt = 0; kt < 4; ++kt) {
      short8 v = bfr[nt][kt];
      #pragma unroll
      for (int e = 0; e < 8; ++e) v[e] = (short)f2b(b2f((u16)v[e]) * ge[e]);
      bfr[nt][kt] = v;
    }

  // ---------- phase B: out GEMM, 4 co-tiles ----------
  #pragma unroll 1
  for (int cb = 0; cb < 4; ++cb) {
    if (cb) __syncthreads();
    const u16* ws2 = WvpT + (size_t)(cb*128 + srow)*128 + shalf*64;
    #pragma unroll
    for (int i = 0; i < 8; ++i) {
      short8 q = *(const short8*)(ws2 + i*8);
      *(short8*)(sdst + ((shalf*128 + i*16) ^ sxor)) = q;
    }
    __syncthreads();

    f32x4 acc2[2][8];
    #pragma unroll
    for (int i = 0; i < 2; ++i)
      #pragma unroll
      for (int j = 0; j < 8; ++j) acc2[i][j] = (f32x4){0.f,0.f,0.f,0.f};

    #pragma unroll
    for (int kt = 0; kt < 4; ++kt) {
      #pragma unroll
      for (int ct = 0; ct < 8; ++ct) {
        const int row = ct*16 + la;
        short8 af = *(const short8*)((const char*)raw + row*256 + ((kt*64 + rg*16) ^ ((row & 7) << 4)));
        acc2[0][ct] = __builtin_amdgcn_mfma_f32_16x16x32_bf16(af, bfr[0][kt], acc2[0][ct], 0, 0, 0);
        acc2[1][ct] = __builtin_amdgcn_mfma_f32_16x16x32_bf16(af, bfr[1][kt], acc2[1][ct], 0, 0, 0);
      }
    }

    #pragma unroll
    for (int nt = 0; nt < 2; ++nt) {
      const size_t row = (size_t)(m0 + w*32 + nt*16 + la);
      #pragma unroll
      for (int ct = 0; ct < 8; ++ct) {
        const int col = cb*128 + ct*16 + rg*4;
        float4 bb = *(const float4*)(bp + col);
        float4 o;
        o.x = acc2[nt][ct][0] + bb.x;
        o.y = acc2[nt][ct][1] + bb.y;
        o.z = acc2[nt][ct][2] + bb.z;
        o.w = acc2[nt][ct][3] + bb.w;
        *(float4*)(out + row*C_ + col) = o;
      }
    }
  }
}

// =================== fallback: validated round-5 path ===================
__global__ __launch_bounds__(256) void fb_prep_kv(
    const float* __restrict__ agent_k, const float* __restrict__ Wk, const float* __restrict__ bk,
    const float* __restrict__ agent_v, const float* __restrict__ Wv, const float* __restrict__ bv,
    float* __restrict__ k2, float* __restrict__ v2)
{
  const int kv = blockIdx.x >> 4;
  const int c0 = (blockIdx.x & 15) * 32;
  const int t = threadIdx.x;
  const float* ag = kv ? agent_v : agent_k;
  const float* W  = kv ? Wv : Wk;
  const float* bb = kv ? bv : bk;
  float* dst      = kv ? v2 : k2;

  __shared__ float ash[16*512];
  __shared__ float part[8][16][32];
  for (int i = t; i < 8192; i += 256) ash[i] = ag[i];
  __syncthreads();

  const int cl = t & 31, ks = t >> 5;
  float s[16];
  #pragma unroll
  for (int a = 0; a < 16; ++a) s[a] = 0.f;
  for (int i = 0; i < 64; ++i) {
    const int cc = ks*64 + i;
    const float wv = W[(size_t)cc*C_ + c0 + cl];
    #pragma unroll
    for (int a = 0; a < 16; ++a) s[a] += ash[a*512 + cc] * wv;
  }
  #pragma unroll
  for (int a = 0; a < 16; ++a) part[ks][a][cl] = s[a];
  __syncthreads();
  for (int p = t; p < 512; p += 256) {
    const int a = p >> 5, c = p & 31;
    float v = bb[c0 + c];
    #pragma unroll
    for (int k = 0; k < 8; ++k) v += part[k][a][c];
    dst[a*C_ + c0 + c] = v;
  }
}

__global__ void fb_prep_wqk(const float* __restrict__ Wq, const float* __restrict__ bq,
                            const float* __restrict__ k2, u16* __restrict__ WqkT, float* __restrict__ bqk)
{
  int c = blockIdx.x, t = threadIdx.x;
  int h = t >> 4, a = t & 15;
  float s = 0.f;
  for (int d = 0; d < 64; ++d) s += Wq[c*C_ + h*64 + d] * k2[a*C_ + h*64 + d];
  WqkT[t*C_ + c] = f2b(s * 0.125f);
  if (c == 0){
    float sb = 0.f;
    for (int d = 0; d < 64; ++d) sb += bq[h*64 + d] * k2[a*C_ + h*64 + d];
    bqk[t] = sb * 0.125f;
  }
}

__global__ void fb_prep_wvp(const float* __restrict__ Wp, const float* __restrict__ v2, u16* __restrict__ WvpT)
{
  int ha = blockIdx.x; int h = ha >> 4, a = ha & 15;
  __shared__ float vsh[64];
  if (threadIdx.x < 64) vsh[threadIdx.x] = v2[a*C_ + h*64 + threadIdx.x];
  __syncthreads();
  for (int co = threadIdx.x; co < C_; co += 256){
    float s = 0.f;
    for (int d = 0; d < 64; ++d) s += vsh[d] * Wp[(h*64 + d)*C_ + co];
    WvpT[co*128 + ha] = f2b(s);
  }
}

__global__ __launch_bounds__(256, 4) void fb_pass_a(
    const float* __restrict__ x, const u16* __restrict__ WqkT,
    const float* __restrict__ bqk, u16* __restrict__ attn,
    float* __restrict__ gpart)
{
  __shared__ u16 Bs[128*128];
  __shared__ float ps[4][16], pm[4][16];

  const int t = threadIdx.x;
  const int m0 = blockIdx.x * 128;
  const int w = t >> 6, lane = t & 63;
  const int la = lane & 15, rg = lane >> 4;

  const float* xr0 = x + (size_t)(m0 + w*32 + la)*C_ + rg*8;
  const float* xr1 = xr0 + 16*C_;

  const int srow = t >> 1, shalf = t & 1;
  const u16* ssrc = WqkT + (size_t)srow*C_ + shalf*64;
  char* sdst = (char*)Bs + srow*256;
  const int sxor = (srow & 7) << 4;

  f32x4 acc[2][8];
  #pragma unroll
  for (int i = 0; i < 2; ++i)
    #pragma unroll
    for (int j = 0; j < 8; ++j) acc[i][j] = (f32x4){0.f,0.f,0.f,0.f};

  float4 pr0[2][2], pr1[2][2];
#define LOADKT(slot, kt) \
  pr0[slot][0] = *(const float4*)(xr0 + (kt)*32);     \
  pr0[slot][1] = *(const float4*)(xr0 + (kt)*32 + 4); \
  pr1[slot][0] = *(const float4*)(xr1 + (kt)*32);     \
  pr1[slot][1] = *(const float4*)(xr1 + (kt)*32 + 4);

  LOADKT(0, 0); LOADKT(1, 1);

  #pragma unroll
  for (int ph = 0; ph < 4; ++ph) {
    __syncthreads();
    #pragma unroll
    for (int i = 0; i < 8; ++i) {
      short8 v = *(const short8*)(ssrc + ph*128 + i*8);
      *(short8*)(sdst + ((shalf*128 + i*16) ^ sxor)) = v;
    }
    __syncthreads();
    #pragma unroll
    for (int k4 = 0; k4 < 4; ++k4) {
      const int kt = ph*4 + k4;
      const int sl = kt & 1;
      short8 b0 = cvt8(pr0[sl][0], pr0[sl][1]);
      short8 b1 = cvt8(pr1[sl][0], pr1[sl][1]);
      if (kt < 14) { LOADKT(sl, kt + 2); }
      #pragma unroll
      for (int ct = 0; ct < 8; ++ct) {
        const int row = ct*16 + la;
        short8 af = *(const short8*)((const char*)Bs + row*256 + ((k4*64 + rg*16) ^ ((row & 7) << 4)));
        acc[0][ct] = __builtin_amdgcn_mfma_f32_16x16x32_bf16(af, b0, acc[0][ct], 0, 0, 0);
        acc[1][ct] = __builtin_amdgcn_mfma_f32_16x16x32_bf16(af, b1, acc[1][ct], 0, 0, 0);
      }
    }
  }
#undef LOADKT

  float psj[4] = {0.f,0.f,0.f,0.f};
  float pmj[4] = {0.f,0.f,0.f,0.f};

  #pragma unroll
  for (int nt = 0; nt < 2; ++nt) {
    const int row = m0 + w*32 + nt*16 + la;
    #pragma unroll
    for (int ct = 0; ct < 8; ++ct) {
      float4 bb = *(const float4*)(bqk + ct*16 + rg*4);
      float e0 = __expf(acc[nt][ct][0] + bb.x);
      float e1 = __expf(acc[nt][ct][1] + bb.y);
      float e2 = __expf(acc[nt][ct][2] + bb.z);
      float e3 = __expf(acc[nt][ct][3] + bb.w);
      float s = e0 + e1 + e2 + e3;
      s += __shfl_xor(s, 16); s += __shfl_xor(s, 32);
      float r = __builtin_amdgcn_rcpf(s);
      float p0 = e0*r, p1 = e1*r, p2 = e2*r, p3 = e3*r;
      psj[0] += p0; psj[1] += p1; psj[2] += p2; psj[3] += p3;
      pmj[0] = fmaxf(pmj[0], p0); pmj[1] = fmaxf(pmj[1], p1);
      pmj[2] = fmaxf(pmj[2], p2); pmj[3] = fmaxf(pmj[3], p3);
      short4_t st;
      st[0]=(short)f2b(p0); st[1]=(short)f2b(p1); st[2]=(short)f2b(p2); st[3]=(short)f2b(p3);
      *(short4_t*)(attn + (size_t)row*128 + ct*16 + rg*4) = st;
    }
  }

  #pragma unroll
  for (int j = 0; j < 4; ++j) {
    float s = psj[j], m = pmj[j];
    s += __shfl_xor(s, 1); s += __shfl_xor(s, 2); s += __shfl_xor(s, 4); s += __shfl_xor(s, 8);
    m = fmaxf(m, __shfl_xor(m, 1)); m = fmaxf(m, __shfl_xor(m, 2));
    m = fmaxf(m, __shfl_xor(m, 4)); m = fmaxf(m, __shfl_xor(m, 8));
    if (la == 0) { ps[w][rg*4+j] = s; pm[w][rg*4+j] = m; }
  }
  __syncthreads();
  if (t < 16) {
    float s = ps[0][t] + ps[1][t] + ps[2][t] + ps[3][t];
    float m = fmaxf(fmaxf(pm[0][t], pm[1][t]), fmaxf(pm[2][t], pm[3][t]));
    gpart[(size_t)blockIdx.x*32 + t]      = s;
    gpart[(size_t)blockIdx.x*32 + 16 + t] = m;
  }
}

__global__ __launch_bounds__(256, 4) void fb_pass_b(
    const u16* __restrict__ attn, const u16* __restrict__ WvpT,
    const float* __restrict__ gpart, const float* __restrict__ ca_w1,
    const float* __restrict__ ca_w2, const float* __restrict__ bp,
    float* __restrict__ out)
{
  __shared__ u16 Bs[128*128];
  __shared__ float gsh[16];
  const int bx = blockIdx.x;
  const int lg = (bx & 7)*512 + (bx >> 3);
  const int mb = lg >> 2, cb = lg & 3;
  const int b = mb >> 5;
  const int t = threadIdx.x;
  const int w = t >> 6, lane = t & 63;
  const int la = lane & 15, rg = lane >> 4;

  const u16* br0 = attn + (size_t)(mb*128 + w*32 + la)*128 + rg*8;
  const u16* br1 = br0 + 16*128;
  short8 bf0[4], bf1[4];
  #pragma unroll
  for (int kt = 0; kt < 4; ++kt) {
    bf0[kt] = *(const short8*)(br0 + kt*32);
    bf1[kt] = *(const short8*)(br1 + kt*32);
  }

  if (t < 16) {
    float s = 0.f, m = 0.f;
    #pragma unroll 4
    for (int blk = 0; blk < 32; ++blk) {
      const float* gp = gpart + (size_t)(b*32 + blk)*32;
      s += gp[t]; m = fmaxf(m, gp[16 + t]);
    }
    float c1 = s * (1.0f/32768.0f) * ca_w1[t];
    float c2 = m * ca_w1[t];
    c1 += __shfl_xor(c1, 1); c1 += __shfl_xor(c1, 2); c1 += __shfl_xor(c1, 4); c1 += __shfl_xor(c1, 8);
    c2 += __shfl_xor(c2, 1); c2 += __shfl_xor(c2, 2); c2 += __shfl_xor(c2, 4); c2 += __shfl_xor(c2, 8);
    float g1 = fmaxf(c1, 0.f) + fmaxf(c2, 0.f);
    gsh[t] = 1.f / (1.f + __expf(-g1 * ca_w2[t]));
  }
  __syncthreads();

  const int srow = t >> 1, shalf = t & 1;
  const u16* ssrc = WvpT + (size_t)(cb*128 + srow)*128 + shalf*64;
  char* sdst = (char*)Bs + srow*256;
  const int sxor = (srow & 7) << 4;
  #pragma unroll
  for (int i = 0; i < 8; ++i) {
    short8 q = *(const short8*)(ssrc + i*8);
    const float* g = &gsh[(i & 1) * 8];
    short8 r;
    #pragma unroll
    for (int j = 0; j < 8; ++j) r[j] = (short)f2b(b2f((u16)q[j]) * g[j]);
    *(short8*)(sdst + ((shalf*128 + i*16) ^ sxor)) = r;
  }
  __syncthreads();

  f32x4 acc[2][8];
  #pragma unroll
  for (int i = 0; i < 2; ++i)
    #pragma unroll
    for (int j = 0; j < 8; ++j) acc[i][j] = (f32x4){0.f,0.f,0.f,0.f};

  #pragma unroll
  for (int kt = 0; kt < 4; ++kt) {
    #pragma unroll
    for (int ct = 0; ct < 8; ++ct) {
      const int row = ct*16 + la;
      short8 af = *(const short8*)((const char*)Bs + row*256 + ((kt*64 + rg*16) ^ ((row & 7) << 4)));
      acc[0][ct] = __builtin_amdgcn_mfma_f32_16x16x32_bf16(af, bf0[kt], acc[0][ct], 0, 0, 0);
      acc[1][ct] = __builtin_amdgcn_mfma_f32_16x16x32_bf16(af, bf1[kt], acc[1][ct], 0, 0, 0);
    }
  }

  #pragma unroll
  for (int nt = 0; nt < 2; ++nt) {
    const size_t row = (size_t)(mb*128 + w*32 + nt*16 + la);
    #pragma unroll
    for (int ct = 0; ct < 8; ++ct) {
      const int col = cb*128 + ct*16 + rg*4;
      float4 bb = *(const float4*)(bp + col);
      float4 o;
      o.x = acc[nt][ct][0] + bb.x;
      o.y = acc[nt][ct][1] + bb.y;
      o.z = acc[nt][ct][2] + bb.z;
      o.w = acc[nt][ct][3] + bb.w;
      *(float4*)(out + row*C_ + col) = o;
    }
  }
}

// ---------------- launch ----------------
extern "C" void kernel_launch(void* const* d_in, const int* in_sizes, int n_in,
                              void* d_out, int out_size, void* d_ws, size_t ws_size,
                              hipStream_t stream)
{
  const float* x       = (const float*)d_in[0];
  const float* Wq      = (const float*)d_in[1];
  const float* bq      = (const float*)d_in[2];
  const float* Wk      = (const float*)d_in[3];
  const float* bk      = (const float*)d_in[4];
  const float* Wv      = (const float*)d_in[5];
  const float* bv      = (const float*)d_in[6];
  const float* Wp      = (const float*)d_in[7];
  const float* bp      = (const float*)d_in[8];
  const float* agent_k = (const float*)d_in[9];
  const float* agent_v = (const float*)d_in[10];
  const float* ca_w1   = (const float*)d_in[11];
  const float* ca_w2   = (const float*)d_in[12];
  float* out = (float*)d_out;

  char* ws = (char*)d_ws;
  u16*   attn  = (u16*)(ws);                          // 33554432 B (fallback only)
  float* k2    = (float*)(ws + 33554432);             // 32768
  float* v2    = (float*)(ws + 33554432 + 32768);     // 32768
  u16*   WqkT  = (u16*)(ws + 33619968);               // 131072
  float* bqk   = (float*)(ws + 33751040);             // 2048
  u16*   WvpT  = (u16*)(ws + 33753088);               // 131072
  float* gpart = (float*)(ws + 33884160);             // 131072

  void* ka[20];
  ka[0]  = (void*)&x;      ka[1]  = (void*)&Wq;     ka[2]  = (void*)&bq;
  ka[3]  = (void*)&Wk;     ka[4]  = (void*)&bk;     ka[5]  = (void*)&Wv;
  ka[6]  = (void*)&bv;     ka[7]  = (void*)&Wp;     ka[8]  = (void*)&bp;
  ka[9]  = (void*)&agent_k; ka[10] = (void*)&agent_v;
  ka[11] = (void*)&ca_w1;  ka[12] = (void*)&ca_w2;  ka[13] = (void*)&out;
  ka[14] = (void*)&k2;     ka[15] = (void*)&v2;     ka[16] = (void*)&WqkT;
  ka[17] = (void*)&bqk;    ka[18] = (void*)&WvpT;   ka[19] = (void*)&gpart;

  hipError_t err = hipLaunchCooperativeKernel(reinterpret_cast<void*>(fused),
                                              dim3(1024), dim3(256), ka, 0u, stream);
  if (err != hipSuccess) {
    (void)hipGetLastError();   // clear
    fb_prep_kv<<<32, 256, 0, stream>>>(agent_k, Wk, bk, agent_v, Wv, bv, k2, v2);
    fb_prep_wqk<<<512, 128, 0, stream>>>(Wq, bq, k2, WqkT, bqk);
    fb_prep_wvp<<<128, 256, 0, stream>>>(Wp, v2, WvpT);
    fb_pass_a<<<1024, 256, 0, stream>>>(x, WqkT, bqk, attn, gpart);
    fb_pass_b<<<4096, 256, 0, stream>>>(attn, WvpT, gpart, ca_w1, ca_w2, bp, out);
  }
}